// Round 9
// baseline (80.681 us; speedup 1.0000x reference)
//
#include <hip/hip_runtime.h>

constexpr float EPS_LN = 1e-5f;

using f32x4 = __attribute__((ext_vector_type(4))) float;
using s16x8 = __attribute__((ext_vector_type(8))) short;

__device__ __forceinline__ short f2bf(float f) {
  union { float f; unsigned u; } v; v.f = f;
  unsigned r = v.u + 0x7fff + ((v.u >> 16) & 1);
  return (short)(r >> 16);
}
__device__ __forceinline__ float bf2f(short h) {
  union { unsigned u; float f; } v;
  v.u = ((unsigned)(unsigned short)h) << 16;
  return v.f;
}

__device__ __forceinline__ s16x8 cvt8(float4 a, float4 b) {
  s16x8 r;
  r[0] = f2bf(a.x); r[1] = f2bf(a.y); r[2] = f2bf(a.z); r[3] = f2bf(a.w);
  r[4] = f2bf(b.x); r[5] = f2bf(b.y); r[6] = f2bf(b.z); r[7] = f2bf(b.w);
  return r;
}

#define MFMA(a, b, c) __builtin_amdgcn_mfma_f32_16x16x32_bf16((a), (b), (c), 0, 0, 0)

__device__ __forceinline__ void gld_lds16(const void* g, void* l) {
  __builtin_amdgcn_global_load_lds(
      (const __attribute__((address_space(1))) unsigned int*)g,
      (__attribute__((address_space(3))) unsigned int*)l, 16, 0, 0);
}

__device__ __forceinline__ void vw0() { asm volatile("s_waitcnt vmcnt(0)" ::: "memory"); }

struct P {
  const int* uid;
  const float *qe, *le, *tab;
  const float *Wu0, *bu0, *Wq0, *bq0, *Wl0, *bl0, *g0, *be0;
  const float *Wu1, *bu1, *Wq1, *bq1, *Wl1, *bl1, *g1, *be1;
  const float *w1, *b1, *w2, *b2;
  short *wt0u, *wt0q, *wt0l, *wt1u, *wt1q, *wt1l, *w1tU, *w1tL;
  short *zA, *uqU, *uqQ;
  float *lw, *b1u, *b1q, *b1l, *lwc, *out;
};

// ---------- ring staging (kc only; verified round 3/8) ----------
template<int NK>
__device__ __forceinline__ void stage_chunk(const short* __restrict__ wt, int kk,
                                            short* dst, int w, int lane) {
  const short* srcbase = wt + (size_t)kk * 8192 + lane * 8;
  #pragma unroll
  for (int s = 0; s < 4; ++s) {
    const int pce = w * 4 + s;
    gld_lds16(srcbase + pce * 512, dst + pce * 512);
  }
  __builtin_amdgcn_sched_barrier(0);
}

template<int NK>
__device__ __forceinline__ void staged_gemm(const short* __restrict__ wt,
                                            const s16x8* aF, short* ring,
                                            int w, int lane, int lr, int lg, int c0,
                                            f32x4 acc[4]) {
  stage_chunk<NK>(wt, 0, ring, w, lane);
  #pragma unroll
  for (int kk = 0; kk < NK; ++kk) {
    short* cur = (kk & 1) ? ring + 8192 : ring;
    short* nxt = (kk & 1) ? ring : ring + 8192;
    if (kk + 1 < NK) {
      stage_chunk<NK>(wt, kk + 1, nxt, w, lane);
      asm volatile("s_waitcnt vmcnt(4)" ::: "memory");
    } else {
      vw0();
    }
    __syncthreads();
    #pragma unroll
    for (int n = 0; n < 4; ++n) {
      const s16x8 bf = *(const s16x8*)&cur[(lg * 256 + c0 + n * 16 + lr) * 8];
      acc[n] = MFMA(aF[kk], bf, acc[n]);
    }
    __syncthreads();
  }
}

// ---------- LN helpers ----------
// plain LayerNorm over 256 cols (affine folded downstream): z <- (z-mu)*rstd
__device__ __forceinline__ void ln16p(float z[4][4], int tid, int w, int lr, int lg,
                                      float (*ssum)[16], float (*ssq)[16],
                                      float* mub, float* rsb) {
  __syncthreads();
  float s1[4] = {0, 0, 0, 0}, s2[4] = {0, 0, 0, 0};
  #pragma unroll
  for (int n = 0; n < 4; ++n)
    #pragma unroll
    for (int r = 0; r < 4; ++r) { s1[r] += z[n][r]; s2[r] += z[n][r] * z[n][r]; }
  #pragma unroll
  for (int off = 1; off < 16; off <<= 1)
    #pragma unroll
    for (int r = 0; r < 4; ++r) {
      s1[r] += __shfl_xor(s1[r], off, 64);
      s2[r] += __shfl_xor(s2[r], off, 64);
    }
  if (lr == 0) {
    #pragma unroll
    for (int r = 0; r < 4; ++r) { ssum[w][lg * 4 + r] = s1[r]; ssq[w][lg * 4 + r] = s2[r]; }
  }
  __syncthreads();
  if (tid < 16) {
    float S1 = 0, S2 = 0;
    #pragma unroll
    for (int ww = 0; ww < 4; ++ww) { S1 += ssum[ww][tid]; S2 += ssq[ww][tid]; }
    float mu = S1 * (1.f / 256.f);
    float var = S2 * (1.f / 256.f) - mu * mu;
    mub[tid] = mu;
    rsb[tid] = rsqrtf(var + EPS_LN);
  }
  __syncthreads();
  #pragma unroll
  for (int n = 0; n < 4; ++n)
    #pragma unroll
    for (int r = 0; r < 4; ++r) {
      const int rr = lg * 4 + r;
      z[n][r] = (z[n][r] - mub[rr]) * rsb[rr];
    }
}

// Normalize one zA row segment in registers -> bf16 A-frags.
// Lane holds row (.. + lr), cols kk*32 + lg*8 + j. Stats across lanes {lr,+16,+32,+48}.
__device__ __forceinline__ void ln_load(const short* __restrict__ zp, s16x8 aF[8]) {
  s16x8 raw[8];
  #pragma unroll
  for (int kk = 0; kk < 8; ++kk) raw[kk] = *(const s16x8*)(zp + kk * 32);
  float s1 = 0.f, s2 = 0.f;
  #pragma unroll
  for (int kk = 0; kk < 8; ++kk)
    #pragma unroll
    for (int j = 0; j < 8; ++j) {
      const float f = bf2f(raw[kk][j]);
      s1 += f; s2 += f * f;
    }
  s1 += __shfl_xor(s1, 16, 64); s2 += __shfl_xor(s2, 16, 64);
  s1 += __shfl_xor(s1, 32, 64); s2 += __shfl_xor(s2, 32, 64);
  const float mu = s1 * (1.f / 256.f);
  const float var = s2 * (1.f / 256.f) - mu * mu;
  const float rs = rsqrtf(var + EPS_LN);
  const float mrs = mu * rs;
  #pragma unroll
  for (int kk = 0; kk < 8; ++kk) {
    s16x8 o;
    #pragma unroll
    for (int j = 0; j < 8; ++j) o[j] = f2bf(bf2f(raw[kk][j]) * rs - mrs);
    aF[kk] = o;
  }
}

__device__ __forceinline__ void store_y(const float z[4][4], short* y_s,
                                        int c0, int lr, int lg) {
  #pragma unroll
  for (int n = 0; n < 4; ++n)
    #pragma unroll
    for (int r = 0; r < 4; ++r)
      y_s[(lg * 4 + r) * 264 + c0 + n * 16 + lr] = f2bf(z[n][r]);
}

__device__ __forceinline__ void load_aF(const short* y_s, s16x8* aF, int lr, int lg) {
  #pragma unroll
  for (int kk = 0; kk < 8; ++kk)
    aF[kk] = *(const s16x8*)&y_s[lr * 264 + kk * 32 + lg * 8];
}

// ---- K0: transpose+cast (+g-fold) weights; blocks >=152 fold biases ----
__global__ __launch_bounds__(256) void k0_kernel(P p) {
  __shared__ float tile[64][65];
  __shared__ float red[4][64];
  int bx = blockIdx.x;
  const int tid = threadIdx.x;
  if (bx >= 152) {
    // bias folds: job 0..2: b1X' = bX1 + be0@WX1 ; job 3: lwc = b1 + be1@w1L + 2*be1@w1U
    const int b = bx - 152;
    const int job = b >> 2, nq = b & 3;
    const int n = nq * 64 + (tid & 63), kp = tid >> 6;
    float s = 0.f;
    if (job < 3) {
      const float* W = (job == 0) ? p.Wu1 : (job == 1) ? p.Wq1 : p.Wl1;
      #pragma unroll 8
      for (int i = 0; i < 64; ++i) {
        const int k = kp * 64 + i;
        s += p.be0[k] * W[(size_t)k * 256 + n];
      }
    } else {
      #pragma unroll 8
      for (int i = 0; i < 128; ++i) {
        const int k = kp * 128 + i;
        const float coef = (k < 256) ? p.be1[k] : 2.f * p.be1[k - 256];
        s += coef * p.w1[(size_t)k * 256 + n];
      }
    }
    red[kp][tid & 63] = s;
    __syncthreads();
    if (kp == 0) {
      float t = red[0][tid] + red[1][tid] + red[2][tid] + red[3][tid];
      if (job == 0)      p.b1u[n] = t + p.bu1[n];
      else if (job == 1) p.b1q[n] = t + p.bq1[n];
      else if (job == 2) p.b1l[n] = t + p.bl1[n];
      else               p.lwc[n] = t + p.b1[n];
    }
    return;
  }
  const float* src;
  short* dst;
  const float* gv = nullptr;
  int rowoff = 0;
  if (bx < 72) {
    const int m = bx / 24; bx -= m * 24;
    src = (m == 0) ? p.Wu0 : (m == 1) ? p.Wq0 : p.Wl0;
    dst = (m == 0) ? p.wt0u : (m == 1) ? p.wt0q : p.wt0l;
  } else if (bx < 120) {
    bx -= 72; const int m = bx / 16; bx -= m * 16;
    src = (m == 0) ? p.Wu1 : (m == 1) ? p.Wq1 : p.Wl1;
    dst = (m == 0) ? p.wt1u : (m == 1) ? p.wt1q : p.wt1l;
    gv = p.g0;
  } else if (bx < 136) {
    bx -= 120; src = p.w1; dst = p.w1tL; gv = p.g1;
  } else {
    bx -= 136; src = p.w1; dst = p.w1tU; gv = p.g1; rowoff = 256;
  }
  const int tn = bx & 3, tk = bx >> 2;
  {
    const int r = tid >> 2, cq = (tid & 3) * 16;
    const float* s = src + (size_t)(rowoff + tk * 64 + r) * 256 + tn * 64 + cq;
    #pragma unroll
    for (int j = 0; j < 4; ++j) {
      float4 v = *(const float4*)(s + j * 4);
      tile[r][cq + j * 4 + 0] = v.x; tile[r][cq + j * 4 + 1] = v.y;
      tile[r][cq + j * 4 + 2] = v.z; tile[r][cq + j * 4 + 3] = v.w;
    }
  }
  __syncthreads();
  {
    const int nn = tid >> 2, kq = (tid & 3) * 16;
    const int n = tn * 64 + nn;
    #pragma unroll
    for (int h = 0; h < 2; ++h) {
      const int kl = kq + h * 8;
      const int kglob = tk * 64 + kl;
      const int kk = kglob >> 5, kg = (kglob & 31) >> 3;
      s16x8 v;
      #pragma unroll
      for (int ko = 0; ko < 8; ++ko) {
        float x = tile[kl + ko][nn];
        if (gv) x *= gv[kglob + ko];
        v[ko] = f2bf(x);
      }
      *(s16x8*)(dst + ((size_t)(kk * 4 + kg) * 256 + n) * 8) = v;
    }
  }
}

// ---- kA: layer0 -> zA (pre-LN, bf16). Resident 48KB weight col-slice.
// u: bx<256 (colgrp=bx&3, rows (bx>>2)*64); q: 256..511; llm: 512..515.
__global__ __launch_bounds__(256) void ka_kernel(P p) {
  __shared__ __align__(16) short wlds[24576];
  const int tid = threadIdx.x, w = tid >> 6, lane = tid & 63;
  const int lr = lane & 15, lg = lane >> 4;
  const int bx = blockIdx.x;
  const short* wt;
  const float* b0;
  int colgrp, zrow0;
  const float* arow;
  if (bx < 256) {
    colgrp = bx & 3;
    const int rb = (bx >> 2) * 64;
    zrow0 = rb;
    wt = p.wt0u; b0 = p.bu0;
    arow = p.tab + (size_t)p.uid[rb + w * 16 + lr] * 384;
  } else if (bx < 512) {
    colgrp = (bx - 256) & 3;
    const int rb = ((bx - 256) >> 2) * 64;
    zrow0 = 4096 + rb;
    wt = p.wt0q; b0 = p.bq0;
    arow = p.qe + (size_t)(rb + w * 16 + lr) * 384;
  } else {
    colgrp = bx - 512;
    zrow0 = 8192;
    wt = p.wt0l; b0 = p.bl0;
    arow = p.le + (size_t)(w * 16 + lr) * 384;
  }
  // one-time stage of the 48KB slice (48 coalesced 1KB pieces)
  #pragma unroll
  for (int s = 0; s < 12; ++s) {
    const int pi = w * 12 + s;
    gld_lds16(wt + (size_t)pi * 2048 + colgrp * 512 + lane * 8, wlds + pi * 512);
  }
  // A-frags (overlaps staging latency)
  s16x8 aF[12];
  #pragma unroll
  for (int kk = 0; kk < 12; ++kk)
    aF[kk] = cvt8(*(const float4*)(arow + kk * 32 + lg * 8),
                  *(const float4*)(arow + kk * 32 + lg * 8 + 4));
  vw0();
  __syncthreads();
  const f32x4 z4 = {0.f, 0.f, 0.f, 0.f};
  f32x4 acc[4] = {z4, z4, z4, z4};
  #pragma unroll
  for (int kk = 0; kk < 12; ++kk)
    #pragma unroll
    for (int n = 0; n < 4; ++n)
      acc[n] = MFMA(aF[kk], *(const s16x8*)&wlds[(kk * 4 + lg) * 512 + (n * 16 + lr) * 8],
                    acc[n]);
  #pragma unroll
  for (int n = 0; n < 4; ++n) {
    const int cg = colgrp * 64 + n * 16 + lr;
    const float bv = b0[cg];
    #pragma unroll
    for (int r = 0; r < 4; ++r)
      p.zA[(size_t)(zrow0 + w * 16 + lg * 4 + r) * 256 + cg] = f2bf(2.f * (acc[n][r] + bv));
  }
}

// ---- kB: layer1. Resident 128KB weight; LN-on-load of zA; plain-LN epilogue.
// bx<128: u rows bx*32 -> uqU ; bx<256: q -> uqQ ; bx 256..259: llm -> lw.
__global__ __launch_bounds__(256) void kb_kernel(P p) {
  __shared__ __align__(16) short wlds[65536];
  __shared__ __align__(16) short y_s[16 * 264];
  __shared__ float ssum[4][16], ssq[4][16], mub[16], rsb[16];
  const int tid = threadIdx.x, w = tid >> 6, lane = tid & 63;
  const int lr = lane & 15, lg = lane >> 4;
  const int c0 = w * 64;
  const int bx = blockIdx.x;
  const f32x4 z4 = {0.f, 0.f, 0.f, 0.f};

  if (bx < 256) {
    const bool isq = bx >= 128;
    const int r0 = (isq ? bx - 128 : bx) * 32;
    const short* wt = isq ? p.wt1q : p.wt1u;
    const float* bvec = isq ? p.b1q : p.b1u;
    short* outB = isq ? p.uqQ : p.uqU;
    const size_t zoff = isq ? 4096 : 0;
    #pragma unroll
    for (int s = 0; s < 32; ++s) {
      const int pi = w * 32 + s;
      gld_lds16(wt + (size_t)pi * 512 + lane * 8, wlds + pi * 512);
    }
    vw0();
    __syncthreads();
    for (int t = 0; t < 2; ++t) {
      const int rows = r0 + t * 16;
      s16x8 aF[8];
      ln_load(p.zA + (size_t)(zoff + rows + lr) * 256 + lg * 8, aF);
      f32x4 acc[4] = {z4, z4, z4, z4};
      #pragma unroll
      for (int kk = 0; kk < 8; ++kk)
        #pragma unroll
        for (int n = 0; n < 4; ++n)
          acc[n] = MFMA(aF[kk],
                        *(const s16x8*)&wlds[kk * 8192 + (lg * 256 + c0 + n * 16 + lr) * 8],
                        acc[n]);
      float z[4][4];
      #pragma unroll
      for (int n = 0; n < 4; ++n) {
        const float bv = bvec[c0 + n * 16 + lr];
        #pragma unroll
        for (int r = 0; r < 4; ++r) z[n][r] = 2.f * (acc[n][r] + bv);
      }
      ln16p(z, tid, w, lr, lg, ssum, ssq, mub, rsb);
      store_y(z, y_s, c0, lr, lg);
      __syncthreads();
      #pragma unroll
      for (int i = 0; i < 2; ++i) {
        const int idx = i * 256 + tid;
        const int row = idx >> 5, cc = (idx & 31) * 8;
        *(s16x8*)(outB + (size_t)(rows + row) * 256 + cc) = *(const s16x8*)&y_s[row * 264 + cc];
      }
      __syncthreads();
    }
  } else {
    const int t = bx - 256;  // llm tile: rows t*16
    #pragma unroll
    for (int s = 0; s < 32; ++s) {
      const int pi = w * 32 + s;
      gld_lds16(p.wt1l + (size_t)pi * 512 + lane * 8, wlds + pi * 512);
    }
    vw0();
    __syncthreads();
    s16x8 aF[8];
    ln_load(p.zA + (size_t)(8192 + t * 16 + lr) * 256 + lg * 8, aF);
    f32x4 acc[4] = {z4, z4, z4, z4};
    #pragma unroll
    for (int kk = 0; kk < 8; ++kk)
      #pragma unroll
      for (int n = 0; n < 4; ++n)
        acc[n] = MFMA(aF[kk],
                      *(const s16x8*)&wlds[kk * 8192 + (lg * 256 + c0 + n * 16 + lr) * 8],
                      acc[n]);
    float z[4][4];
    #pragma unroll
    for (int n = 0; n < 4; ++n) {
      const float bv = p.b1l[c0 + n * 16 + lr];
      #pragma unroll
      for (int r = 0; r < 4; ++r) z[n][r] = 2.f * (acc[n][r] + bv);
    }
    ln16p(z, tid, w, lr, lg, ssum, ssq, mub, rsb);
    store_y(z, y_s, c0, lr, lg);
    __syncthreads();
    load_aF(y_s, aF, lr, lg);
    // restage with w1tL' (safe: all wlds reads completed before the sync above)
    #pragma unroll
    for (int s = 0; s < 32; ++s) {
      const int pi = w * 32 + s;
      gld_lds16(p.w1tL + (size_t)pi * 512 + lane * 8, wlds + pi * 512);
    }
    vw0();
    __syncthreads();
    f32x4 acc2[4] = {z4, z4, z4, z4};
    #pragma unroll
    for (int kk = 0; kk < 8; ++kk)
      #pragma unroll
      for (int n = 0; n < 4; ++n)
        acc2[n] = MFMA(aF[kk],
                       *(const s16x8*)&wlds[kk * 8192 + (lg * 256 + c0 + n * 16 + lr) * 8],
                       acc2[n]);
    #pragma unroll
    for (int n = 0; n < 4; ++n) {
      const int c = c0 + n * 16 + lr;
      const float cv = p.lwc[c];
      #pragma unroll
      for (int r = 0; r < 4; ++r)
        p.lw[(size_t)(t * 16 + lg * 4 + r) * 256 + c] = acc2[n][r] + cv;
    }
  }
}

// ---- kC: GEMM2 (A = uqU+uqQ) + fused score (round-8 structure) ----
__global__ __launch_bounds__(256, 1) void kc_kernel(P p) {
  __shared__ __align__(16) short ring[4 * 8192];
  __shared__ __align__(16) float lw_s[64 * 256];
  __shared__ __align__(16) float uqw_s[16 * 260];
  __shared__ float w2s[256];
  const int tid = threadIdx.x, w = tid >> 6, lane = tid & 63;
  const int lr = lane & 15, lg = lane >> 4;
  const int c0 = w * 64;
  const int r0 = blockIdx.x * 16;

  #pragma unroll
  for (int s = 0; s < 16; ++s) {
    const int i = w * 16 + s;
    gld_lds16(p.lw + (size_t)i * 256 + ((lane ^ (i & 7)) << 2),
              (char*)lw_s + (size_t)i * 1024);
  }
  __builtin_amdgcn_sched_barrier(0);
  w2s[tid] = p.w2[tid];

  s16x8 aF[8];
  {
    const s16x8* pu = (const s16x8*)(p.uqU + (size_t)(r0 + lr) * 256);
    const s16x8* pq = (const s16x8*)(p.uqQ + (size_t)(r0 + lr) * 256);
    #pragma unroll
    for (int kk = 0; kk < 8; ++kk) {
      const s16x8 a = pu[kk * 4 + lg], b = pq[kk * 4 + lg];
      s16x8 o;
      #pragma unroll
      for (int j = 0; j < 8; ++j) o[j] = f2bf(bf2f(a[j]) + bf2f(b[j]));
      aF[kk] = o;
    }
  }
  const f32x4 z4 = {0.f, 0.f, 0.f, 0.f};
  f32x4 acc[4] = {z4, z4, z4, z4};
  staged_gemm<8>(p.w1tU, aF, ring, w, lane, lr, lg, c0, acc);
  #pragma unroll
  for (int n = 0; n < 4; ++n)
    #pragma unroll
    for (int r = 0; r < 4; ++r)
      uqw_s[(lg * 4 + r) * 260 + c0 + n * 16 + lr] = acc[n][r];
  __syncthreads();

  const float b2v = p.b2[0];
  const int l = lane;
  float sacc[4] = {0.f, 0.f, 0.f, 0.f};
  #pragma unroll 4
  for (int jj = 0; jj < 64; ++jj) {
    const float4 lwv = *(const float4*)&lw_s[l * 256 + ((jj ^ (l & 7)) << 2)];
    const float4 w2v = *(const float4*)&w2s[jj * 4];
    #pragma unroll
    for (int bi = 0; bi < 4; ++bi) {
      const float4 uqv = *(const float4*)&uqw_s[(w * 4 + bi) * 260 + jj * 4];
      sacc[bi] += fmaxf(lwv.x + uqv.x, 0.f) * w2v.x;
      sacc[bi] += fmaxf(lwv.y + uqv.y, 0.f) * w2v.y;
      sacc[bi] += fmaxf(lwv.z + uqv.z, 0.f) * w2v.z;
      sacc[bi] += fmaxf(lwv.w + uqv.w, 0.f) * w2v.w;
    }
  }
  #pragma unroll
  for (int bi = 0; bi < 4; ++bi)
    p.out[(size_t)(r0 + w * 4 + bi) * 64 + l] = sacc[bi] + b2v;
}

extern "C" void kernel_launch(void* const* d_in, const int* in_sizes, int n_in,
                              void* d_out, int out_size, void* d_ws, size_t ws_size,
                              hipStream_t stream) {
  (void)in_sizes; (void)n_in; (void)out_size; (void)ws_size;
  P p;
  p.uid = (const int*)d_in[0];
  p.qe  = (const float*)d_in[1];
  p.le  = (const float*)d_in[2];
  p.tab = (const float*)d_in[3];
  p.Wu0 = (const float*)d_in[4];  p.bu0 = (const float*)d_in[5];
  p.Wq0 = (const float*)d_in[6];  p.bq0 = (const float*)d_in[7];
  p.Wl0 = (const float*)d_in[8];  p.bl0 = (const float*)d_in[9];
  p.g0  = (const float*)d_in[10]; p.be0 = (const float*)d_in[11];
  p.Wu1 = (const float*)d_in[12]; p.bu1 = (const float*)d_in[13];
  p.Wq1 = (const float*)d_in[14]; p.bq1 = (const float*)d_in[15];
  p.Wl1 = (const float*)d_in[16]; p.bl1 = (const float*)d_in[17];
  p.g1  = (const float*)d_in[18]; p.be1 = (const float*)d_in[19];
  p.w1  = (const float*)d_in[20]; p.b1  = (const float*)d_in[21];
  p.w2  = (const float*)d_in[22]; p.b2  = (const float*)d_in[23];

  short* wsS = (short*)d_ws;
  size_t o = 0;
  p.wt0u = wsS + o; o += 98304;    // 12 chunks x 8192 shorts (K=384)
  p.wt0q = wsS + o; o += 98304;
  p.wt0l = wsS + o; o += 98304;
  p.wt1u = wsS + o; o += 65536;    // 8 chunks x 8192 (K=256, g0-folded)
  p.wt1q = wsS + o; o += 65536;
  p.wt1l = wsS + o; o += 65536;
  p.w1tU = wsS + o; o += 65536;    // g1-folded
  p.w1tL = wsS + o; o += 65536;    // g1-folded
  p.zA   = wsS + o; o += 2113536;  // 8256x256 bf16 pre-LN z (u|q|llm)
  p.uqU  = wsS + o; o += 1048576;  // 4096x256 bf16 normalized u1
  p.uqQ  = wsS + o; o += 1048576;  // 4096x256 bf16 normalized q1
  float* wsF = (float*)(wsS + o);
  p.lw  = wsF;            // 64x256
  p.b1u = wsF + 16384;
  p.b1q = wsF + 16640;
  p.b1l = wsF + 16896;
  p.lwc = wsF + 17152;
  p.out = (float*)d_out;

  hipLaunchKernelGGL(k0_kernel, dim3(168), dim3(256), 0, stream, p);
  hipLaunchKernelGGL(ka_kernel, dim3(516), dim3(256), 0, stream, p);
  hipLaunchKernelGGL(kb_kernel, dim3(260), dim3(256), 0, stream, p);
  hipLaunchKernelGGL(kc_kernel, dim3(256), dim3(256), 0, stream, p);
}

// Round 10
// 50.341 us; speedup vs baseline: 1.6027x; 1.6027x over previous
//
#include <hip/hip_runtime.h>

constexpr float EPS_LN = 1e-5f;

using f32x4 = __attribute__((ext_vector_type(4))) float;
using s16x8 = __attribute__((ext_vector_type(8))) short;

__device__ __forceinline__ short f2bf(float f) {
  union { float f; unsigned u; } v; v.f = f;
  unsigned r = v.u + 0x7fff + ((v.u >> 16) & 1);
  return (short)(r >> 16);
}

__device__ __forceinline__ s16x8 cvt8(float4 a, float4 b) {
  s16x8 r;
  r[0] = f2bf(a.x); r[1] = f2bf(a.y); r[2] = f2bf(a.z); r[3] = f2bf(a.w);
  r[4] = f2bf(b.x); r[5] = f2bf(b.y); r[6] = f2bf(b.z); r[7] = f2bf(b.w);
  return r;
}

#define MFMA(a, b, c) __builtin_amdgcn_mfma_f32_16x16x32_bf16((a), (b), (c), 0, 0, 0)

__device__ __forceinline__ void gld_lds16(const void* g, void* l) {
  __builtin_amdgcn_global_load_lds(
      (const __attribute__((address_space(1))) unsigned int*)g,
      (__attribute__((address_space(3))) unsigned int*)l, 16, 0, 0);
}

struct P {
  const int* uid;
  const float *qe, *le, *tab;
  const float *Wu0, *bu0, *Wq0, *bq0, *Wl0, *bl0, *g0, *be0;
  const float *Wu1, *bu1, *Wq1, *bq1, *Wl1, *bl1, *g1, *be1;
  const float *w1, *b1, *w2, *b2;
  short *wt0u, *wt0q, *wt0l, *wt1u, *wt1q, *wt1l, *w1tU, *w1tL;
  short *y0, *uqB;
  float *lw, *out;
};

// Direct global->VGPR B-fragment GEMM over the chunk-sequential swizzled
// weight layout (short idx = kk*8192 + (kg*256 + col)*8 + ko). Lane (lr,lg)
// reads 16B at (lg*256 + c0 + n*16 + lr)*8 -> lanes lr=0..15 contiguous 256B,
// 4 lg segments per instruction: coalesced. No LDS, no barriers -> compiler
// hoists loads across steps and waves slip freely (TLP hides L2 latency).
// Replaces round-8's ring staging whose 3-step issue-to-use distance
// (~600cy) < L2/L3 latency made every step arrival-bound.
template<int NK>
__device__ __forceinline__ void dgemm(const short* __restrict__ wt,
                                      const s16x8* aF, int lg, int lr, int c0,
                                      f32x4 acc[4]) {
  #pragma unroll
  for (int kk = 0; kk < NK; ++kk) {
    const short* base = wt + (size_t)kk * 8192 + (size_t)(lg * 256 + c0 + lr) * 8;
    #pragma unroll
    for (int n = 0; n < 4; ++n) {
      const s16x8 bf = *(const s16x8*)(base + n * 128);
      acc[n] = MFMA(aF[kk], bf, acc[n]);
    }
  }
}

// LayerNorm over 256 cols; in-place on z[n][r] (col=c0+n*16+lr, row=lg*4+r).
__device__ __forceinline__ void ln16(float z[4][4], int tid, int w, int lr, int lg,
                                     int c0, const float* __restrict__ g,
                                     const float* __restrict__ be,
                                     float (*ssum)[16], float (*ssq)[16],
                                     float* mub, float* rsb) {
  __syncthreads();
  float s1[4] = {0, 0, 0, 0}, s2[4] = {0, 0, 0, 0};
  #pragma unroll
  for (int n = 0; n < 4; ++n)
    #pragma unroll
    for (int r = 0; r < 4; ++r) { s1[r] += z[n][r]; s2[r] += z[n][r] * z[n][r]; }
  #pragma unroll
  for (int off = 1; off < 16; off <<= 1)
    #pragma unroll
    for (int r = 0; r < 4; ++r) {
      s1[r] += __shfl_xor(s1[r], off, 64);
      s2[r] += __shfl_xor(s2[r], off, 64);
    }
  if (lr == 0) {
    #pragma unroll
    for (int r = 0; r < 4; ++r) { ssum[w][lg * 4 + r] = s1[r]; ssq[w][lg * 4 + r] = s2[r]; }
  }
  __syncthreads();
  if (tid < 16) {
    float S1 = 0, S2 = 0;
    #pragma unroll
    for (int ww = 0; ww < 4; ++ww) { S1 += ssum[ww][tid]; S2 += ssq[ww][tid]; }
    float mu = S1 * (1.f / 256.f);
    float var = S2 * (1.f / 256.f) - mu * mu;
    mub[tid] = mu;
    rsb[tid] = rsqrtf(var + EPS_LN);
  }
  __syncthreads();
  #pragma unroll
  for (int n = 0; n < 4; ++n) {
    const int c = c0 + n * 16 + lr;
    const float gv = g[c], bv = be[c];
    #pragma unroll
    for (int r = 0; r < 4; ++r) {
      const int rr = lg * 4 + r;
      z[n][r] = gv * (z[n][r] - mub[rr]) * rsb[rr] + bv;
    }
  }
}

__device__ __forceinline__ void bias2(const f32x4 acc[4], const float* __restrict__ b,
                                      int c0, int lr, float z[4][4]) {
  #pragma unroll
  for (int n = 0; n < 4; ++n) {
    const float bv = b[c0 + n * 16 + lr];
    #pragma unroll
    for (int r = 0; r < 4; ++r) z[n][r] = 2.f * (acc[n][r] + bv);
  }
}

__device__ __forceinline__ void store_y(const float z[4][4], short* y_s,
                                        int c0, int lr, int lg) {
  #pragma unroll
  for (int n = 0; n < 4; ++n)
    #pragma unroll
    for (int r = 0; r < 4; ++r)
      y_s[(lg * 4 + r) * 264 + c0 + n * 16 + lr] = f2bf(z[n][r]);
}

__device__ __forceinline__ void load_aF(const short* y_s, s16x8* aF, int lr, int lg) {
  #pragma unroll
  for (int kk = 0; kk < 8; ++kk)
    aF[kk] = *(const s16x8*)&y_s[lr * 264 + kk * 32 + lg * 8];
}

// ---- K0: tiled transpose+cast into the CHUNK-SEQUENTIAL swizzled layout ----
// out short idx = ((kk*4+kg)*256 + n)*8 + ko, where k = kk*32+kg*8+ko.
__global__ __launch_bounds__(256) void k0_kernel(P p) {
  __shared__ float tile[64][65];
  int bx = blockIdx.x;
  const int tid = threadIdx.x;
  const float* src;
  short* dst;
  int rowoff = 0;
  if (bx < 72) {
    const int m = bx / 24; bx -= m * 24;
    src = (m == 0) ? p.Wu0 : (m == 1) ? p.Wq0 : p.Wl0;
    dst = (m == 0) ? p.wt0u : (m == 1) ? p.wt0q : p.wt0l;
  } else if (bx < 120) {
    bx -= 72; const int m = bx / 16; bx -= m * 16;
    src = (m == 0) ? p.Wu1 : (m == 1) ? p.Wq1 : p.Wl1;
    dst = (m == 0) ? p.wt1u : (m == 1) ? p.wt1q : p.wt1l;
  } else if (bx < 136) {
    bx -= 120; src = p.w1; dst = p.w1tL;
  } else {
    bx -= 136; src = p.w1; dst = p.w1tU; rowoff = 256;
  }
  const int tn = bx & 3, tk = bx >> 2;
  {
    const int r = tid >> 2, cq = (tid & 3) * 16;
    const float* s = src + (size_t)(rowoff + tk * 64 + r) * 256 + tn * 64 + cq;
    #pragma unroll
    for (int j = 0; j < 4; ++j) {
      float4 v = *(const float4*)(s + j * 4);
      tile[r][cq + j * 4 + 0] = v.x; tile[r][cq + j * 4 + 1] = v.y;
      tile[r][cq + j * 4 + 2] = v.z; tile[r][cq + j * 4 + 3] = v.w;
    }
  }
  __syncthreads();
  {
    const int nn = tid >> 2, kq = (tid & 3) * 16;
    const int n = tn * 64 + nn;
    #pragma unroll
    for (int h = 0; h < 2; ++h) {
      const int kl = kq + h * 8;
      const int kglob = tk * 64 + kl;
      const int kk = kglob >> 5, kg = (kglob & 31) >> 3;
      s16x8 v;
      #pragma unroll
      for (int ko = 0; ko < 8; ++ko) v[ko] = f2bf(tile[kl + ko][nn]);
      *(s16x8*)(dst + ((size_t)(kk * 4 + kg) * 256 + n) * 8) = v;
    }
  }
}

// ---- kA: layer0 for u (0..255), q (256..511), llm (512..515) -> y0 [8256][256]
__global__ __launch_bounds__(256) void ka_kernel(P p) {
  __shared__ __align__(16) short y_s[16 * 264];
  __shared__ float ssum[4][16], ssq[4][16], mub[16], rsb[16];
  const int tid = threadIdx.x, w = tid >> 6, lane = tid & 63;
  const int lr = lane & 15, lg = lane >> 4;
  const int c0 = w * 64;
  const int t = blockIdx.x;
  const int r0 = t * 16;
  const float* arow;
  const short* wt;
  const float* bias;
  if (t < 256)      { arow = p.tab + (size_t)p.uid[r0 + lr] * 384; wt = p.wt0u; bias = p.bu0; }
  else if (t < 512) { arow = p.qe + (size_t)(r0 - 4096 + lr) * 384; wt = p.wt0q; bias = p.bq0; }
  else              { arow = p.le + (size_t)((t - 512) * 16 + lr) * 384; wt = p.wt0l; bias = p.bl0; }
  s16x8 aF[12];
  #pragma unroll
  for (int kk = 0; kk < 12; ++kk)
    aF[kk] = cvt8(*(const float4*)(arow + kk * 32 + lg * 8),
                  *(const float4*)(arow + kk * 32 + lg * 8 + 4));
  const f32x4 z4 = {0.f, 0.f, 0.f, 0.f};
  f32x4 acc[4] = {z4, z4, z4, z4};
  dgemm<12>(wt, aF, lg, lr, c0, acc);
  float z[4][4];
  bias2(acc, bias, c0, lr, z);
  ln16(z, tid, w, lr, lg, c0, p.g0, p.be0, ssum, ssq, mub, rsb);
  store_y(z, y_s, c0, lr, lg);
  __syncthreads();
  #pragma unroll
  for (int i = 0; i < 2; ++i) {
    const int idx = i * 256 + tid;  // 512 pieces of 16B
    const int row = idx >> 5, cc = (idx & 31) * 8;
    *(s16x8*)(p.y0 + (size_t)(r0 + row) * 256 + cc) = *(const s16x8*)&y_s[row * 264 + cc];
  }
}

// ---- kB: 0..255 = u/q layer1 + add -> uqB; 256..259 = llm layer1 + w1tL -> lw
__global__ __launch_bounds__(256) void kb_kernel(P p) {
  __shared__ __align__(16) short y_s[16 * 264];
  __shared__ float ssum[4][16], ssq[4][16], mub[16], rsb[16];
  const int tid = threadIdx.x, w = tid >> 6, lane = tid & 63;
  const int lr = lane & 15, lg = lane >> 4;
  const int c0 = w * 64;
  const int bx = blockIdx.x;
  const f32x4 z4 = {0.f, 0.f, 0.f, 0.f};

  if (bx < 256) {
    const int r0 = bx * 16;
    s16x8 aF[8];
    {
      const s16x8* ap = (const s16x8*)(p.y0 + (size_t)(r0 + lr) * 256);
      #pragma unroll
      for (int kk = 0; kk < 8; ++kk) aF[kk] = ap[kk * 4 + lg];
    }
    f32x4 accU[4] = {z4, z4, z4, z4};
    dgemm<8>(p.wt1u, aF, lg, lr, c0, accU);
    {
      const s16x8* ap = (const s16x8*)(p.y0 + (size_t)(4096 + r0 + lr) * 256);
      #pragma unroll
      for (int kk = 0; kk < 8; ++kk) aF[kk] = ap[kk * 4 + lg];
    }
    f32x4 accQ[4] = {z4, z4, z4, z4};
    dgemm<8>(p.wt1q, aF, lg, lr, c0, accQ);
    float z[4][4], zq[4][4];
    bias2(accU, p.bu1, c0, lr, z);
    ln16(z, tid, w, lr, lg, c0, p.g1, p.be1, ssum, ssq, mub, rsb);
    bias2(accQ, p.bq1, c0, lr, zq);
    ln16(zq, tid, w, lr, lg, c0, p.g1, p.be1, ssum, ssq, mub, rsb);
    #pragma unroll
    for (int n = 0; n < 4; ++n)
      #pragma unroll
      for (int r = 0; r < 4; ++r) z[n][r] += zq[n][r];
    store_y(z, y_s, c0, lr, lg);
    __syncthreads();
    #pragma unroll
    for (int i = 0; i < 2; ++i) {
      const int idx = i * 256 + tid;
      const int row = idx >> 5, cc = (idx & 31) * 8;
      *(s16x8*)(p.uqB + (size_t)(r0 + row) * 256 + cc) = *(const s16x8*)&y_s[row * 264 + cc];
    }
  } else {
    const int rb = (bx - 256) * 16;
    s16x8 aF[8];
    {
      const s16x8* ap = (const s16x8*)(p.y0 + (size_t)(8192 + rb + lr) * 256);
      #pragma unroll
      for (int kk = 0; kk < 8; ++kk) aF[kk] = ap[kk * 4 + lg];
    }
    f32x4 acc[4] = {z4, z4, z4, z4};
    dgemm<8>(p.wt1l, aF, lg, lr, c0, acc);
    float z[4][4];
    bias2(acc, p.bl1, c0, lr, z);
    ln16(z, tid, w, lr, lg, c0, p.g1, p.be1, ssum, ssq, mub, rsb);
    store_y(z, y_s, c0, lr, lg);
    __syncthreads();
    load_aF(y_s, aF, lr, lg);
    #pragma unroll
    for (int n = 0; n < 4; ++n) acc[n] = z4;
    dgemm<8>(p.w1tL, aF, lg, lr, c0, acc);
    #pragma unroll
    for (int n = 0; n < 4; ++n) {
      const int c = c0 + n * 16 + lr;
      const float bv = p.b1[c];
      #pragma unroll
      for (int r = 0; r < 4; ++r)
        p.lw[(size_t)(rb + lg * 4 + r) * 256 + c] = acc[n][r] + bv;
    }
  }
}

// ---- kC: GEMM2 (uq @ w1[256:,:]) kept in LDS + fused score -> out ----
__global__ __launch_bounds__(256, 1) void kc_kernel(P p) {
  __shared__ __align__(16) float lw_s[64 * 256];
  __shared__ __align__(16) float uqw_s[16 * 260];
  __shared__ float w2s[256];
  const int tid = threadIdx.x, w = tid >> 6, lane = tid & 63;
  const int lr = lane & 15, lg = lane >> 4;
  const int c0 = w * 64;
  const int r0 = blockIdx.x * 16;

  // stage lw (64KB fp32) with XOR-swizzled source (both-sides swizzle);
  // drained by the __syncthreads() before the score phase.
  #pragma unroll
  for (int s = 0; s < 16; ++s) {
    const int i = w * 16 + s;  // lw row
    gld_lds16(p.lw + (size_t)i * 256 + ((lane ^ (i & 7)) << 2),
              (char*)lw_s + (size_t)i * 1024);
  }
  __builtin_amdgcn_sched_barrier(0);
  w2s[tid] = p.w2[tid];

  s16x8 aF[8];
  {
    const s16x8* ap = (const s16x8*)(p.uqB + (size_t)(r0 + lr) * 256);
    #pragma unroll
    for (int kk = 0; kk < 8; ++kk) aF[kk] = ap[kk * 4 + lg];
  }
  const f32x4 z4 = {0.f, 0.f, 0.f, 0.f};
  f32x4 acc[4] = {z4, z4, z4, z4};
  dgemm<8>(p.w1tU, aF, lg, lr, c0, acc);
  #pragma unroll
  for (int n = 0; n < 4; ++n)
    #pragma unroll
    for (int r = 0; r < 4; ++r)
      uqw_s[(lg * 4 + r) * 260 + c0 + n * 16 + lr] = acc[n][r];
  __syncthreads();  // drains vm (incl. lw_s global_load_lds) + lgkm

  // score: out[b][l] = sum_j relu(lw[l][j]+uqw[b][j])*w2[j] + b2
  const float b2v = p.b2[0];
  const int l = lane;
  float sacc[4] = {0.f, 0.f, 0.f, 0.f};
  #pragma unroll 4
  for (int jj = 0; jj < 64; ++jj) {
    const float4 lwv = *(const float4*)&lw_s[l * 256 + ((jj ^ (l & 7)) << 2)];
    const float4 w2v = *(const float4*)&w2s[jj * 4];
    #pragma unroll
    for (int bi = 0; bi < 4; ++bi) {
      const float4 uqv = *(const float4*)&uqw_s[(w * 4 + bi) * 260 + jj * 4];
      sacc[bi] += fmaxf(lwv.x + uqv.x, 0.f) * w2v.x;
      sacc[bi] += fmaxf(lwv.y + uqv.y, 0.f) * w2v.y;
      sacc[bi] += fmaxf(lwv.z + uqv.z, 0.f) * w2v.z;
      sacc[bi] += fmaxf(lwv.w + uqv.w, 0.f) * w2v.w;
    }
  }
  #pragma unroll
  for (int bi = 0; bi < 4; ++bi)
    p.out[(size_t)(r0 + w * 4 + bi) * 64 + l] = sacc[bi] + b2v;
}

extern "C" void kernel_launch(void* const* d_in, const int* in_sizes, int n_in,
                              void* d_out, int out_size, void* d_ws, size_t ws_size,
                              hipStream_t stream) {
  (void)in_sizes; (void)n_in; (void)out_size; (void)ws_size;
  P p;
  p.uid = (const int*)d_in[0];
  p.qe  = (const float*)d_in[1];
  p.le  = (const float*)d_in[2];
  p.tab = (const float*)d_in[3];
  p.Wu0 = (const float*)d_in[4];  p.bu0 = (const float*)d_in[5];
  p.Wq0 = (const float*)d_in[6];  p.bq0 = (const float*)d_in[7];
  p.Wl0 = (const float*)d_in[8];  p.bl0 = (const float*)d_in[9];
  p.g0  = (const float*)d_in[10]; p.be0 = (const float*)d_in[11];
  p.Wu1 = (const float*)d_in[12]; p.bu1 = (const float*)d_in[13];
  p.Wq1 = (const float*)d_in[14]; p.bq1 = (const float*)d_in[15];
  p.Wl1 = (const float*)d_in[16]; p.bl1 = (const float*)d_in[17];
  p.g1  = (const float*)d_in[18]; p.be1 = (const float*)d_in[19];
  p.w1  = (const float*)d_in[20]; p.b1  = (const float*)d_in[21];
  p.w2  = (const float*)d_in[22]; p.b2  = (const float*)d_in[23];

  short* wsS = (short*)d_ws;
  size_t o = 0;
  p.wt0u = wsS + o; o += 98304;    // 12 chunks x 8192 shorts (K=384)
  p.wt0q = wsS + o; o += 98304;
  p.wt0l = wsS + o; o += 98304;
  p.wt1u = wsS + o; o += 65536;    // 8 chunks x 8192 (K=256)
  p.wt1q = wsS + o; o += 65536;
  p.wt1l = wsS + o; o += 65536;
  p.w1tU = wsS + o; o += 65536;    // w1[256:512] swizzled
  p.w1tL = wsS + o; o += 65536;    // w1[0:256] swizzled
  p.y0   = wsS + o; o += 2113536;  // 8256x256 bf16 (u 0..4095, q 4096..8191, llm 8192..8255)
  p.uqB  = wsS + o; o += 1048576;  // 4096x256 bf16
  p.lw   = (float*)(wsS + o);      // 64x256 fp32 (16B-aligned byte offset)
  p.out  = (float*)d_out;

  hipLaunchKernelGGL(k0_kernel, dim3(152), dim3(256), 0, stream, p);
  hipLaunchKernelGGL(ka_kernel, dim3(516), dim3(256), 0, stream, p);
  hipLaunchKernelGGL(kb_kernel, dim3(260), dim3(256), 0, stream, p);
  hipLaunchKernelGGL(kc_kernel, dim3(256), dim3(256), 0, stream, p);
}

// Round 11
// 50.218 us; speedup vs baseline: 1.6066x; 1.0024x over previous
//
#include <hip/hip_runtime.h>

constexpr float EPS_LN = 1e-5f;

using f32x4 = __attribute__((ext_vector_type(4))) float;
using s16x8 = __attribute__((ext_vector_type(8))) short;

__device__ __forceinline__ short f2bf(float f) {
  union { float f; unsigned u; } v; v.f = f;
  unsigned r = v.u + 0x7fff + ((v.u >> 16) & 1);
  return (short)(r >> 16);
}

__device__ __forceinline__ s16x8 cvt8(float4 a, float4 b) {
  s16x8 r;
  r[0] = f2bf(a.x); r[1] = f2bf(a.y); r[2] = f2bf(a.z); r[3] = f2bf(a.w);
  r[4] = f2bf(b.x); r[5] = f2bf(b.y); r[6] = f2bf(b.z); r[7] = f2bf(b.w);
  return r;
}

#define MFMA(a, b, c) __builtin_amdgcn_mfma_f32_16x16x32_bf16((a), (b), (c), 0, 0, 0)

__device__ __forceinline__ void gld_lds16(const void* g, void* l) {
  __builtin_amdgcn_global_load_lds(
      (const __attribute__((address_space(1))) unsigned int*)g,
      (__attribute__((address_space(3))) unsigned int*)l, 16, 0, 0);
}

struct P {
  const int* uid;
  const float *qe, *le, *tab;
  const float *Wu0, *bu0, *Wq0, *bq0, *Wl0, *bl0, *g0, *be0;
  const float *Wu1, *bu1, *Wq1, *bq1, *Wl1, *bl1, *g1, *be1;
  const float *w1, *b1, *w2, *b2;
  short *wt0u, *wt0q, *wt0l, *wt1u, *wt1q, *wt1l, *w1tU, *w1tL;
  short *y0, *uqB;
  float *lw, *out;
};

// Direct global->VGPR B-fragment GEMM over the chunk-sequential swizzled
// weight layout (short idx = kk*8192 + (kg*256 + col)*8 + ko), with an
// EXPLICIT 4-slot register pipeline: B-fragments for steps kk..kk+3 are in
// flight simultaneously (12-16 outstanding dwordx4 loads), hiding ~200cy
// L2-hit latency at 2 waves/SIMD occupancy. All B[] indices are
// compile-time after full unroll (rule #20: no dynamic-indexed regs).
template<int NK>
__device__ __forceinline__ void dgemm(const short* __restrict__ wt,
                                      const s16x8* aF, int lg, int lr, int c0,
                                      f32x4 acc[4]) {
  const short* base = wt + (size_t)(lg * 256 + c0 + lr) * 8;
  s16x8 B[4][4];
  #pragma unroll
  for (int pk = 0; pk < 3; ++pk) {
    if (pk < NK) {
      #pragma unroll
      for (int n = 0; n < 4; ++n)
        B[pk][n] = *(const s16x8*)(base + (size_t)pk * 8192 + n * 128);
    }
  }
  #pragma unroll
  for (int kk = 0; kk < NK; ++kk) {
    if (kk + 3 < NK) {
      #pragma unroll
      for (int n = 0; n < 4; ++n)
        B[(kk + 3) & 3][n] = *(const s16x8*)(base + (size_t)(kk + 3) * 8192 + n * 128);
    }
    #pragma unroll
    for (int n = 0; n < 4; ++n)
      acc[n] = MFMA(aF[kk], B[kk & 3][n], acc[n]);
  }
}

// LayerNorm over 256 cols; in-place on z[n][r] (col=c0+n*16+lr, row=lg*4+r).
__device__ __forceinline__ void ln16(float z[4][4], int tid, int w, int lr, int lg,
                                     int c0, const float* __restrict__ g,
                                     const float* __restrict__ be,
                                     float (*ssum)[16], float (*ssq)[16],
                                     float* mub, float* rsb) {
  __syncthreads();
  float s1[4] = {0, 0, 0, 0}, s2[4] = {0, 0, 0, 0};
  #pragma unroll
  for (int n = 0; n < 4; ++n)
    #pragma unroll
    for (int r = 0; r < 4; ++r) { s1[r] += z[n][r]; s2[r] += z[n][r] * z[n][r]; }
  #pragma unroll
  for (int off = 1; off < 16; off <<= 1)
    #pragma unroll
    for (int r = 0; r < 4; ++r) {
      s1[r] += __shfl_xor(s1[r], off, 64);
      s2[r] += __shfl_xor(s2[r], off, 64);
    }
  if (lr == 0) {
    #pragma unroll
    for (int r = 0; r < 4; ++r) { ssum[w][lg * 4 + r] = s1[r]; ssq[w][lg * 4 + r] = s2[r]; }
  }
  __syncthreads();
  if (tid < 16) {
    float S1 = 0, S2 = 0;
    #pragma unroll
    for (int ww = 0; ww < 4; ++ww) { S1 += ssum[ww][tid]; S2 += ssq[ww][tid]; }
    float mu = S1 * (1.f / 256.f);
    float var = S2 * (1.f / 256.f) - mu * mu;
    mub[tid] = mu;
    rsb[tid] = rsqrtf(var + EPS_LN);
  }
  __syncthreads();
  #pragma unroll
  for (int n = 0; n < 4; ++n) {
    const int c = c0 + n * 16 + lr;
    const float gv = g[c], bv = be[c];
    #pragma unroll
    for (int r = 0; r < 4; ++r) {
      const int rr = lg * 4 + r;
      z[n][r] = gv * (z[n][r] - mub[rr]) * rsb[rr] + bv;
    }
  }
}

__device__ __forceinline__ void bias2(const f32x4 acc[4], const float* __restrict__ b,
                                      int c0, int lr, float z[4][4]) {
  #pragma unroll
  for (int n = 0; n < 4; ++n) {
    const float bv = b[c0 + n * 16 + lr];
    #pragma unroll
    for (int r = 0; r < 4; ++r) z[n][r] = 2.f * (acc[n][r] + bv);
  }
}

__device__ __forceinline__ void store_y(const float z[4][4], short* y_s,
                                        int c0, int lr, int lg) {
  #pragma unroll
  for (int n = 0; n < 4; ++n)
    #pragma unroll
    for (int r = 0; r < 4; ++r)
      y_s[(lg * 4 + r) * 264 + c0 + n * 16 + lr] = f2bf(z[n][r]);
}

__device__ __forceinline__ void load_aF(const short* y_s, s16x8* aF, int lr, int lg) {
  #pragma unroll
  for (int kk = 0; kk < 8; ++kk)
    aF[kk] = *(const s16x8*)&y_s[lr * 264 + kk * 32 + lg * 8];
}

// ---- K0: tiled transpose+cast into the CHUNK-SEQUENTIAL swizzled layout ----
// out short idx = ((kk*4+kg)*256 + n)*8 + ko, where k = kk*32+kg*8+ko.
__global__ __launch_bounds__(256) void k0_kernel(P p) {
  __shared__ float tile[64][65];
  int bx = blockIdx.x;
  const int tid = threadIdx.x;
  const float* src;
  short* dst;
  int rowoff = 0;
  if (bx < 72) {
    const int m = bx / 24; bx -= m * 24;
    src = (m == 0) ? p.Wu0 : (m == 1) ? p.Wq0 : p.Wl0;
    dst = (m == 0) ? p.wt0u : (m == 1) ? p.wt0q : p.wt0l;
  } else if (bx < 120) {
    bx -= 72; const int m = bx / 16; bx -= m * 16;
    src = (m == 0) ? p.Wu1 : (m == 1) ? p.Wq1 : p.Wl1;
    dst = (m == 0) ? p.wt1u : (m == 1) ? p.wt1q : p.wt1l;
  } else if (bx < 136) {
    bx -= 120; src = p.w1; dst = p.w1tL;
  } else {
    bx -= 136; src = p.w1; dst = p.w1tU; rowoff = 256;
  }
  const int tn = bx & 3, tk = bx >> 2;
  {
    const int r = tid >> 2, cq = (tid & 3) * 16;
    const float* s = src + (size_t)(rowoff + tk * 64 + r) * 256 + tn * 64 + cq;
    #pragma unroll
    for (int j = 0; j < 4; ++j) {
      float4 v = *(const float4*)(s + j * 4);
      tile[r][cq + j * 4 + 0] = v.x; tile[r][cq + j * 4 + 1] = v.y;
      tile[r][cq + j * 4 + 2] = v.z; tile[r][cq + j * 4 + 3] = v.w;
    }
  }
  __syncthreads();
  {
    const int nn = tid >> 2, kq = (tid & 3) * 16;
    const int n = tn * 64 + nn;
    #pragma unroll
    for (int h = 0; h < 2; ++h) {
      const int kl = kq + h * 8;
      const int kglob = tk * 64 + kl;
      const int kk = kglob >> 5, kg = (kglob & 31) >> 3;
      s16x8 v;
      #pragma unroll
      for (int ko = 0; ko < 8; ++ko) v[ko] = f2bf(tile[kl + ko][nn]);
      *(s16x8*)(dst + ((size_t)(kk * 4 + kg) * 256 + n) * 8) = v;
    }
  }
}

// ---- kA: layer0 for u (0..255), q (256..511), llm (512..515) -> y0 [8256][256]
__global__ __launch_bounds__(256) void ka_kernel(P p) {
  __shared__ __align__(16) short y_s[16 * 264];
  __shared__ float ssum[4][16], ssq[4][16], mub[16], rsb[16];
  const int tid = threadIdx.x, w = tid >> 6, lane = tid & 63;
  const int lr = lane & 15, lg = lane >> 4;
  const int c0 = w * 64;
  const int t = blockIdx.x;
  const int r0 = t * 16;
  const float* arow;
  const short* wt;
  const float* bias;
  if (t < 256)      { arow = p.tab + (size_t)p.uid[r0 + lr] * 384; wt = p.wt0u; bias = p.bu0; }
  else if (t < 512) { arow = p.qe + (size_t)(r0 - 4096 + lr) * 384; wt = p.wt0q; bias = p.bq0; }
  else              { arow = p.le + (size_t)((t - 512) * 16 + lr) * 384; wt = p.wt0l; bias = p.bl0; }
  s16x8 aF[12];
  #pragma unroll
  for (int kk = 0; kk < 12; ++kk)
    aF[kk] = cvt8(*(const float4*)(arow + kk * 32 + lg * 8),
                  *(const float4*)(arow + kk * 32 + lg * 8 + 4));
  const f32x4 z4 = {0.f, 0.f, 0.f, 0.f};
  f32x4 acc[4] = {z4, z4, z4, z4};
  dgemm<12>(wt, aF, lg, lr, c0, acc);
  float z[4][4];
  bias2(acc, bias, c0, lr, z);
  ln16(z, tid, w, lr, lg, c0, p.g0, p.be0, ssum, ssq, mub, rsb);
  store_y(z, y_s, c0, lr, lg);
  __syncthreads();
  #pragma unroll
  for (int i = 0; i < 2; ++i) {
    const int idx = i * 256 + tid;  // 512 pieces of 16B
    const int row = idx >> 5, cc = (idx & 31) * 8;
    *(s16x8*)(p.y0 + (size_t)(r0 + row) * 256 + cc) = *(const s16x8*)&y_s[row * 264 + cc];
  }
}

// ---- kB: 0..255 = u/q layer1 + add -> uqB; 256..259 = llm layer1 + w1tL -> lw
__global__ __launch_bounds__(256) void kb_kernel(P p) {
  __shared__ __align__(16) short y_s[16 * 264];
  __shared__ float ssum[4][16], ssq[4][16], mub[16], rsb[16];
  const int tid = threadIdx.x, w = tid >> 6, lane = tid & 63;
  const int lr = lane & 15, lg = lane >> 4;
  const int c0 = w * 64;
  const int bx = blockIdx.x;
  const f32x4 z4 = {0.f, 0.f, 0.f, 0.f};

  if (bx < 256) {
    const int r0 = bx * 16;
    s16x8 aF[8];
    {
      const s16x8* ap = (const s16x8*)(p.y0 + (size_t)(r0 + lr) * 256);
      #pragma unroll
      for (int kk = 0; kk < 8; ++kk) aF[kk] = ap[kk * 4 + lg];
    }
    f32x4 accU[4] = {z4, z4, z4, z4};
    dgemm<8>(p.wt1u, aF, lg, lr, c0, accU);
    {
      const s16x8* ap = (const s16x8*)(p.y0 + (size_t)(4096 + r0 + lr) * 256);
      #pragma unroll
      for (int kk = 0; kk < 8; ++kk) aF[kk] = ap[kk * 4 + lg];
    }
    f32x4 accQ[4] = {z4, z4, z4, z4};
    dgemm<8>(p.wt1q, aF, lg, lr, c0, accQ);
    float z[4][4], zq[4][4];
    bias2(accU, p.bu1, c0, lr, z);
    ln16(z, tid, w, lr, lg, c0, p.g1, p.be1, ssum, ssq, mub, rsb);
    bias2(accQ, p.bq1, c0, lr, zq);
    ln16(zq, tid, w, lr, lg, c0, p.g1, p.be1, ssum, ssq, mub, rsb);
    #pragma unroll
    for (int n = 0; n < 4; ++n)
      #pragma unroll
      for (int r = 0; r < 4; ++r) z[n][r] += zq[n][r];
    store_y(z, y_s, c0, lr, lg);
    __syncthreads();
    #pragma unroll
    for (int i = 0; i < 2; ++i) {
      const int idx = i * 256 + tid;
      const int row = idx >> 5, cc = (idx & 31) * 8;
      *(s16x8*)(p.uqB + (size_t)(r0 + row) * 256 + cc) = *(const s16x8*)&y_s[row * 264 + cc];
    }
  } else {
    const int rb = (bx - 256) * 16;
    s16x8 aF[8];
    {
      const s16x8* ap = (const s16x8*)(p.y0 + (size_t)(8192 + rb + lr) * 256);
      #pragma unroll
      for (int kk = 0; kk < 8; ++kk) aF[kk] = ap[kk * 4 + lg];
    }
    f32x4 acc[4] = {z4, z4, z4, z4};
    dgemm<8>(p.wt1l, aF, lg, lr, c0, acc);
    float z[4][4];
    bias2(acc, p.bl1, c0, lr, z);
    ln16(z, tid, w, lr, lg, c0, p.g1, p.be1, ssum, ssq, mub, rsb);
    store_y(z, y_s, c0, lr, lg);
    __syncthreads();
    load_aF(y_s, aF, lr, lg);
    #pragma unroll
    for (int n = 0; n < 4; ++n) acc[n] = z4;
    dgemm<8>(p.w1tL, aF, lg, lr, c0, acc);
    #pragma unroll
    for (int n = 0; n < 4; ++n) {
      const int c = c0 + n * 16 + lr;
      const float bv = p.b1[c];
      #pragma unroll
      for (int r = 0; r < 4; ++r)
        p.lw[(size_t)(rb + lg * 4 + r) * 256 + c] = acc[n][r] + bv;
    }
  }
}

// ---- kC: GEMM2 (uq @ w1[256:,:]) kept in LDS + fused score -> out ----
__global__ __launch_bounds__(256, 1) void kc_kernel(P p) {
  __shared__ __align__(16) float lw_s[64 * 256];
  __shared__ __align__(16) float uqw_s[16 * 260];
  __shared__ float w2s[256];
  const int tid = threadIdx.x, w = tid >> 6, lane = tid & 63;
  const int lr = lane & 15, lg = lane >> 4;
  const int c0 = w * 64;
  const int r0 = blockIdx.x * 16;

  // stage lw (64KB fp32) with XOR-swizzled source (both-sides swizzle);
  // drained by the __syncthreads() before the score phase.
  #pragma unroll
  for (int s = 0; s < 16; ++s) {
    const int i = w * 16 + s;  // lw row
    gld_lds16(p.lw + (size_t)i * 256 + ((lane ^ (i & 7)) << 2),
              (char*)lw_s + (size_t)i * 1024);
  }
  __builtin_amdgcn_sched_barrier(0);
  w2s[tid] = p.w2[tid];

  s16x8 aF[8];
  {
    const s16x8* ap = (const s16x8*)(p.uqB + (size_t)(r0 + lr) * 256);
    #pragma unroll
    for (int kk = 0; kk < 8; ++kk) aF[kk] = ap[kk * 4 + lg];
  }
  const f32x4 z4 = {0.f, 0.f, 0.f, 0.f};
  f32x4 acc[4] = {z4, z4, z4, z4};
  dgemm<8>(p.w1tU, aF, lg, lr, c0, acc);
  #pragma unroll
  for (int n = 0; n < 4; ++n)
    #pragma unroll
    for (int r = 0; r < 4; ++r)
      uqw_s[(lg * 4 + r) * 260 + c0 + n * 16 + lr] = acc[n][r];
  __syncthreads();  // drains vm (incl. lw_s global_load_lds) + lgkm

  // score: out[b][l] = sum_j relu(lw[l][j]+uqw[b][j])*w2[j] + b2
  const float b2v = p.b2[0];
  const int l = lane;
  float sacc[4] = {0.f, 0.f, 0.f, 0.f};
  #pragma unroll 4
  for (int jj = 0; jj < 64; ++jj) {
    const float4 lwv = *(const float4*)&lw_s[l * 256 + ((jj ^ (l & 7)) << 2)];
    const float4 w2v = *(const float4*)&w2s[jj * 4];
    #pragma unroll
    for (int bi = 0; bi < 4; ++bi) {
      const float4 uqv = *(const float4*)&uqw_s[(w * 4 + bi) * 260 + jj * 4];
      sacc[bi] += fmaxf(lwv.x + uqv.x, 0.f) * w2v.x;
      sacc[bi] += fmaxf(lwv.y + uqv.y, 0.f) * w2v.y;
      sacc[bi] += fmaxf(lwv.z + uqv.z, 0.f) * w2v.z;
      sacc[bi] += fmaxf(lwv.w + uqv.w, 0.f) * w2v.w;
    }
  }
  #pragma unroll
  for (int bi = 0; bi < 4; ++bi)
    p.out[(size_t)(r0 + w * 4 + bi) * 64 + l] = sacc[bi] + b2v;
}

extern "C" void kernel_launch(void* const* d_in, const int* in_sizes, int n_in,
                              void* d_out, int out_size, void* d_ws, size_t ws_size,
                              hipStream_t stream) {
  (void)in_sizes; (void)n_in; (void)out_size; (void)ws_size;
  P p;
  p.uid = (const int*)d_in[0];
  p.qe  = (const float*)d_in[1];
  p.le  = (const float*)d_in[2];
  p.tab = (const float*)d_in[3];
  p.Wu0 = (const float*)d_in[4];  p.bu0 = (const float*)d_in[5];
  p.Wq0 = (const float*)d_in[6];  p.bq0 = (const float*)d_in[7];
  p.Wl0 = (const float*)d_in[8];  p.bl0 = (const float*)d_in[9];
  p.g0  = (const float*)d_in[10]; p.be0 = (const float*)d_in[11];
  p.Wu1 = (const float*)d_in[12]; p.bu1 = (const float*)d_in[13];
  p.Wq1 = (const float*)d_in[14]; p.bq1 = (const float*)d_in[15];
  p.Wl1 = (const float*)d_in[16]; p.bl1 = (const float*)d_in[17];
  p.g1  = (const float*)d_in[18]; p.be1 = (const float*)d_in[19];
  p.w1  = (const float*)d_in[20]; p.b1  = (const float*)d_in[21];
  p.w2  = (const float*)d_in[22]; p.b2  = (const float*)d_in[23];

  short* wsS = (short*)d_ws;
  size_t o = 0;
  p.wt0u = wsS + o; o += 98304;    // 12 chunks x 8192 shorts (K=384)
  p.wt0q = wsS + o; o += 98304;
  p.wt0l = wsS + o; o += 98304;
  p.wt1u = wsS + o; o += 65536;    // 8 chunks x 8192 (K=256)
  p.wt1q = wsS + o; o += 65536;
  p.wt1l = wsS + o; o += 65536;
  p.w1tU = wsS + o; o += 65536;    // w1[256:512] swizzled
  p.w1tL = wsS + o; o += 65536;    // w1[0:256] swizzled
  p.y0   = wsS + o; o += 2113536;  // 8256x256 bf16 (u 0..4095, q 4096..8191, llm 8192..8255)
  p.uqB  = wsS + o; o += 1048576;  // 4096x256 bf16
  p.lw   = (float*)(wsS + o);      // 64x256 fp32 (16B-aligned byte offset)
  p.out  = (float*)d_out;

  hipLaunchKernelGGL(k0_kernel, dim3(152), dim3(256), 0, stream, p);
  hipLaunchKernelGGL(ka_kernel, dim3(516), dim3(256), 0, stream, p);
  hipLaunchKernelGGL(kb_kernel, dim3(260), dim3(256), 0, stream, p);
  hipLaunchKernelGGL(kc_kernel, dim3(256), dim3(256), 0, stream, p);
}